// Round 1
// 679.831 us; speedup vs baseline: 2.2759x; 2.2759x over previous
//
#include <hip/hip_runtime.h>

// Anti-alias filter: reflect-pad -> grouped conv (256->72, G=8, 3x3) -> BN ->
// softmax(72) -> per-pixel 9-tap weighted sum per channel.
// Shapes fixed: N=16, C=256, H=W=128, G=8, K=3, NCH=G*K*K=72, CPG=32.
//
// Structure (v2): 8 threads per pixel, one per group. Block = 512 threads =
// 64 consecutive pixels x 8 groups, arranged so each WAVE owns one group
// (g = tid>>6 is wave-uniform -> conv weights stay s_load'ed). This cuts
// per-thread live state from 72 accumulators (spilled: VGPR_Count was 68)
// to 9, and raises the grid from 1024 to 4096 blocks for latency hiding.
// Softmax over the 72 channels = 8-way cross-wave LDS reduction.

#define NN    16
#define CTOT  256
#define HH    128
#define WW    128
#define NG    8
#define CPG   32      // channels per group
#define NCH   72      // G*K*K conv output channels
#define BN_EPS 1e-5f

// ---- prep: BN scale/bias into ws ----
// ws layout (floats): [0,72) = scale, [72,144) = bias.
__global__ void aaf_prep(const float* __restrict__ gamma,
                         const float* __restrict__ beta,
                         const float* __restrict__ rmean,
                         const float* __restrict__ rvar,
                         float* __restrict__ ws) {
    int t = threadIdx.x;
    if (t < NCH) {
        float sc = gamma[t] * rsqrtf(rvar[t] + BN_EPS);
        ws[t]       = sc;
        ws[NCH + t] = beta[t] - rmean[t] * sc;
    }
}

// ---- main: block = 64 pixels x 8 groups (one wave per group) ----
__global__ __launch_bounds__(512, 4) void aaf_main(
    const float* __restrict__ x,
    const float* __restrict__ wf,     // fp32 conv weights OIHW flat (wave-uniform -> s_load)
    const float* __restrict__ scale,  // fp32 BN scale (72)
    const float* __restrict__ bias,   // fp32 BN bias  (72)
    float* __restrict__ out) {

    __shared__ float red[NG][64];     // cross-wave softmax reduction

    int p = threadIdx.x & 63;                                   // pixel lane 0..63
    int g = __builtin_amdgcn_readfirstlane((int)threadIdx.x >> 6); // group = wave id (uniform)

    int idx = blockIdx.x * 64 + p;    // n*H*W + h*W + w ; 64 | W so h,n uniform per block
    int n  = idx >> 14;               // H*W = 16384 = 2^14
    int hw = idx & 16383;
    int h  = hw >> 7;
    int w  = hw & 127;

    // reflection-pad neighbor indices (pad=1): -1 -> 1, 128 -> 126
    int ys[3], xs[3];
    ys[0] = (h == 0)   ? 1   : h - 1;
    ys[1] = h;
    ys[2] = (h == 127) ? 126 : h + 1;
    xs[0] = (w == 0)   ? 1   : w - 1;
    xs[1] = w;
    xs[2] = (w == 127) ? 126 : w + 1;

    // this wave's 32 input channels start at g*CPG
    const float* xg = x + ((size_t)n << 22) + ((size_t)(g * CPG) << 14);

    float sig[9];
#pragma unroll
    for (int o = 0; o < 9; o++) sig[o] = 0.f;

    // ---- grouped conv: sig[o] = sum_{ci,tap} x * w  (this wave's group only) ----
    for (int ci = 0; ci < CPG; ci++) {
        const float* xc = xg + ((size_t)ci << 14);
        float v[9];
#pragma unroll
        for (int ky = 0; ky < 3; ky++) {
            int rb = ys[ky] << 7;
#pragma unroll
            for (int kx = 0; kx < 3; kx++)
                v[ky * 3 + kx] = xc[rb + xs[kx]];
        }
        // weights: wf[(g*9+o)*288 + ci*9 + tap] — wave-uniform indices -> s_load
        const float* wb = wf + (size_t)(g * 9) * (CPG * 9) + ci * 9;
#pragma unroll
        for (int o = 0; o < 9; o++) {
            float a = sig[o];
#pragma unroll
            for (int tp = 0; tp < 9; tp++)
                a = fmaf(v[tp], wb[o * (CPG * 9) + tp], a);
            sig[o] = a;
        }
    }

    // ---- BN + local max ----
    float mx = -3.0e38f;
#pragma unroll
    for (int o = 0; o < 9; o++) {
        sig[o] = fmaf(sig[o], scale[g * 9 + o], bias[g * 9 + o]);
        mx = fmaxf(mx, sig[o]);
    }

    // ---- softmax over all 72 channels: 8-way cross-wave reduction ----
    red[g][p] = mx;
    __syncthreads();
    float gmx = red[0][p];
#pragma unroll
    for (int r = 1; r < NG; r++) gmx = fmaxf(gmx, red[r][p]);
    __syncthreads();                  // all reads done before red is reused

    float s = 0.f;
#pragma unroll
    for (int o = 0; o < 9; o++) {
        sig[o] = __expf(sig[o] - gmx);
        s += sig[o];
    }
    red[g][p] = s;
    __syncthreads();
    float tot = red[0][p];
#pragma unroll
    for (int r = 1; r < NG; r++) tot += red[r][p];
    float inv = 1.f / tot;
#pragma unroll
    for (int o = 0; o < 9; o++) sig[o] *= inv;

    // ---- weighted 9-tap sum for this wave's 32 channels ----
    size_t obase = ((size_t)n << 22) + ((size_t)(g * CPG) << 14) + (size_t)hw;
    for (int ci = 0; ci < CPG; ci++) {
        const float* xc = xg + ((size_t)ci << 14);
        float a = 0.f;
#pragma unroll
        for (int ky = 0; ky < 3; ky++) {
            int rb = ys[ky] << 7;
#pragma unroll
            for (int kx = 0; kx < 3; kx++)
                a = fmaf(xc[rb + xs[kx]], sig[ky * 3 + kx], a);
        }
        out[obase + ((size_t)ci << 14)] = a;
    }
}

extern "C" void kernel_launch(void* const* d_in, const int* in_sizes, int n_in,
                              void* d_out, int out_size, void* d_ws, size_t ws_size,
                              hipStream_t stream) {
    const float* x     = (const float*)d_in[0];
    const float* cw    = (const float*)d_in[1];
    const float* gamma = (const float*)d_in[2];
    const float* beta  = (const float*)d_in[3];
    const float* rmean = (const float*)d_in[4];
    const float* rvar  = (const float*)d_in[5];
    float* out = (float*)d_out;
    float* ws  = (float*)d_ws;   // needs 144*4 = 576 B

    hipLaunchKernelGGL(aaf_prep, dim3(1), dim3(128), 0, stream,
                       gamma, beta, rmean, rvar, ws);

    int pixels = NN * HH * WW;                    // 262144
    int blocks = pixels * NG / 512;               // 4096 blocks of 512 (64 px x 8 grp)
    hipLaunchKernelGGL(aaf_main, dim3(blocks), dim3(512), 0, stream,
                       x, cw, ws, ws + NCH, out);
}

// Round 2
// 649.304 us; speedup vs baseline: 2.3829x; 1.0470x over previous
//
#include <hip/hip_runtime.h>

// Anti-alias filter: reflect-pad -> grouped conv (256->72, G=8, 3x3) -> BN ->
// softmax(72) -> per-pixel 9-tap weighted sum per channel.
// Shapes fixed: N=16, C=256, H=W=128, G=8, K=3, NCH=G*K*K=72, CPG=32.
//
// v3: single-barrier fused softmax. Softmax factorizes per group:
//   out[c] = (sum_tap x[c,tap]*E[g,tap]) / (sum_g' S_g' * exp(m_g' - m_g))
// with E = exp(l - m_g), S_g = sum E. So each wave (owning one group) runs
// conv -> E -> immediately re-reads its taps (cache-hot) into 32 register
// accumulators, THEN one barrier to exchange the 8 (m,S) scalar pairs and
// rescale in registers. This removes the block-wide barrier between the two
// x-reading phases (the 4.5x fetch amplification in v2).
// Also: bijective XCD-chunked block swizzle (vertical row reuse lands in the
// same XCD L2) and nontemporal stores for out.

#define NN    16
#define CTOT  256
#define HH    128
#define WW    128
#define NG    8
#define CPG   32      // channels per group
#define NCH   72      // G*K*K conv output channels
#define BN_EPS 1e-5f

// ---- prep: BN scale/bias into ws ----
// ws layout (floats): [0,72) = scale, [72,144) = bias.
__global__ void aaf_prep(const float* __restrict__ gamma,
                         const float* __restrict__ beta,
                         const float* __restrict__ rmean,
                         const float* __restrict__ rvar,
                         float* __restrict__ ws) {
    int t = threadIdx.x;
    if (t < NCH) {
        float sc = gamma[t] * rsqrtf(rvar[t] + BN_EPS);
        ws[t]       = sc;
        ws[NCH + t] = beta[t] - rmean[t] * sc;
    }
}

// ---- main: block = 64 pixels x 8 groups (one wave per group) ----
__global__ __launch_bounds__(512, 4) void aaf_main(
    const float* __restrict__ x,
    const float* __restrict__ wf,     // fp32 conv weights OIHW flat (wave-uniform -> s_load)
    const float* __restrict__ scale,  // fp32 BN scale (72)
    const float* __restrict__ bias,   // fp32 BN bias  (72)
    float* __restrict__ out) {

    __shared__ float red_m[NG][64];   // per-group softmax max, per pixel
    __shared__ float red_s[NG][64];   // per-group exp-sum, per pixel

    int p = threadIdx.x & 63;                                      // pixel lane 0..63
    int g = __builtin_amdgcn_readfirstlane((int)threadIdx.x >> 6); // group = wave id (uniform)

    // XCD-chunked bijective swizzle: 4096 blocks = 8 XCDs x 512 consecutive.
    // Each XCD walks 2 images' rows in order -> rows h-1/h/h+1 reuse hits its L2.
    int bid = blockIdx.x;
    int swz = (bid & 7) * (4096 / 8) + (bid >> 3);

    int idx = swz * 64 + p;           // n*H*W + h*W + w ; 64 | W so h,n uniform per block
    int n  = idx >> 14;               // H*W = 16384 = 2^14
    int hw = idx & 16383;
    int h  = hw >> 7;
    int w  = hw & 127;

    // reflection-pad neighbor indices (pad=1): -1 -> 1, 128 -> 126
    int ys[3], xs[3];
    ys[0] = (h == 0)   ? 1   : h - 1;
    ys[1] = h;
    ys[2] = (h == 127) ? 126 : h + 1;
    xs[0] = (w == 0)   ? 1   : w - 1;
    xs[1] = w;
    xs[2] = (w == 127) ? 126 : w + 1;

    // this wave's 32 input channels start at g*CPG
    const float* xg = x + ((size_t)n << 22) + ((size_t)(g * CPG) << 14);

    float sig[9];
#pragma unroll
    for (int o = 0; o < 9; o++) sig[o] = 0.f;

    // ---- grouped conv: sig[o] = sum_{ci,tap} x * w  (this wave's group only) ----
    for (int ci = 0; ci < CPG; ci++) {
        const float* xc = xg + ((size_t)ci << 14);
        float v[9];
#pragma unroll
        for (int ky = 0; ky < 3; ky++) {
            int rb = ys[ky] << 7;
#pragma unroll
            for (int kx = 0; kx < 3; kx++)
                v[ky * 3 + kx] = xc[rb + xs[kx]];
        }
        // weights: wf[(g*9+o)*288 + ci*9 + tap] — wave-uniform indices -> s_load
        const float* wb = wf + (size_t)(g * 9) * (CPG * 9) + ci * 9;
#pragma unroll
        for (int o = 0; o < 9; o++) {
            float a = sig[o];
#pragma unroll
            for (int tp = 0; tp < 9; tp++)
                a = fmaf(v[tp], wb[o * (CPG * 9) + tp], a);
            sig[o] = a;
        }
    }

    // ---- BN + per-group (unnormalized) softmax: E[o], m, S ----
    float m = -3.0e38f;
#pragma unroll
    for (int o = 0; o < 9; o++) {
        sig[o] = fmaf(sig[o], scale[g * 9 + o], bias[g * 9 + o]);
        m = fmaxf(m, sig[o]);
    }
    float E[9];
    float S = 0.f;
#pragma unroll
    for (int o = 0; o < 9; o++) {
        E[o] = __expf(sig[o] - m);
        S += E[o];
    }
    red_m[g][p] = m;     // own rows only; consumed after the single barrier below
    red_s[g][p] = S;

    // ---- fused weighted 9-tap sum (unnormalized) into registers ----
    // Re-reads the same taps the conv just touched (cache-hot: no intervening
    // barrier). Fully unrolled so acc[] stays in VGPRs (rule #20).
    float acc[CPG];
#pragma unroll
    for (int ci = 0; ci < CPG; ci++) {
        const float* xc = xg + ((size_t)ci << 14);
        float a = 0.f;
#pragma unroll
        for (int ky = 0; ky < 3; ky++) {
            int rb = ys[ky] << 7;
#pragma unroll
            for (int kx = 0; kx < 3; kx++)
                a = fmaf(xc[rb + xs[kx]], E[ky * 3 + kx], a);
        }
        acc[ci] = a;
    }

    // ---- single barrier: combine per-group (m,S) into the normalization ----
    __syncthreads();
    float denom = 0.f;
#pragma unroll
    for (int r = 0; r < NG; r++)
        denom += red_s[r][p] * __expf(red_m[r][p] - m);
    float inv = 1.f / denom;          // == 1 / sum_all exp(l' - m_g)

    size_t obase = ((size_t)n << 22) + ((size_t)(g * CPG) << 14) + (size_t)hw;
#pragma unroll
    for (int ci = 0; ci < CPG; ci++)
        __builtin_nontemporal_store(acc[ci] * inv, &out[obase + ((size_t)ci << 14)]);
}

extern "C" void kernel_launch(void* const* d_in, const int* in_sizes, int n_in,
                              void* d_out, int out_size, void* d_ws, size_t ws_size,
                              hipStream_t stream) {
    const float* x     = (const float*)d_in[0];
    const float* cw    = (const float*)d_in[1];
    const float* gamma = (const float*)d_in[2];
    const float* beta  = (const float*)d_in[3];
    const float* rmean = (const float*)d_in[4];
    const float* rvar  = (const float*)d_in[5];
    float* out = (float*)d_out;
    float* ws  = (float*)d_ws;   // needs 144*4 = 576 B

    hipLaunchKernelGGL(aaf_prep, dim3(1), dim3(128), 0, stream,
                       gamma, beta, rmean, rvar, ws);

    int pixels = NN * HH * WW;                    // 262144
    int blocks = pixels * NG / 512;               // 4096 blocks of 512 (64 px x 8 grp)
    hipLaunchKernelGGL(aaf_main, dim3(blocks), dim3(512), 0, stream,
                       x, cw, ws, ws + NCH, out);
}

// Round 4
// 545.159 us; speedup vs baseline: 2.8382x; 1.1910x over previous
//
#include <hip/hip_runtime.h>

// Anti-alias filter: reflect-pad -> grouped conv (256->72, G=8, 3x3) -> BN ->
// softmax(72) -> per-pixel 9-tap weighted sum per channel.
// Shapes fixed: N=16, C=256, H=W=128, G=8, K=3, NCH=G*K*K=72, CPG=32.
//
// v4b: row-per-wave + float2 + shfl neighbor exchange.
// Each wave owns (one group) x (one full image row): 64 lanes x 2 px.
// Per (channel,row) a lane issues ONE aligned 8B load; horizontal
// neighbors come from __shfl_up/__shfl_down. Reflection padding is free:
//   lane 0:  __shfl_up(b,1) returns own b = x[1]  == reflect(x[-1])
//   lane 63: __shfl_down(a,1) returns own a = x[126] == reflect(x[128])
// This cuts vmem instructions ~12x vs v3 (576 scalar loads/px -> 96 x 8B
// per 2px) — v3's counters showed we were vmem-issue/latency bound, not
// HBM bound (FETCH 171 MB, 15% BW, VALUBusy 39%).
// Softmax: per-group (m,S) in registers, ONE barrier to combine the 8
// groups' scalars, 1/denom folded into E -> no acc[] array, low VGPR.
// (v4 compile fix: nontemporal_store needs a NATIVE vector type, not
// HIP_vector_type<float,2> -> use ext_vector_type(2).)

#define NN    16
#define CTOT  256
#define HH    128
#define WW    128
#define NG    8
#define CPG   32      // channels per group
#define NCH   72      // G*K*K conv output channels
#define BN_EPS 1e-5f

typedef float f2 __attribute__((ext_vector_type(2)));

// ---- prep: BN scale/bias into ws ----
// ws layout (floats): [0,72) = scale, [72,144) = bias.
__global__ void aaf_prep(const float* __restrict__ gamma,
                         const float* __restrict__ beta,
                         const float* __restrict__ rmean,
                         const float* __restrict__ rvar,
                         float* __restrict__ ws) {
    int t = threadIdx.x;
    if (t < NCH) {
        float sc = gamma[t] * rsqrtf(rvar[t] + BN_EPS);
        ws[t]       = sc;
        ws[NCH + t] = beta[t] - rmean[t] * sc;
    }
}

// ---- main: block = 8 waves = 8 groups, each wave = one full row (128 px) ----
__global__ __launch_bounds__(512, 4) void aaf_main(
    const float* __restrict__ x,
    const float* __restrict__ wf,     // fp32 conv weights OIHW flat (wave-uniform -> s_load)
    const float* __restrict__ scale,  // fp32 BN scale (72)
    const float* __restrict__ bias,   // fp32 BN bias  (72)
    float* __restrict__ out) {

    __shared__ float red_m[NG][WW];   // per-group softmax max, per pixel (4 KB)
    __shared__ float red_s[NG][WW];   // per-group exp-sum, per pixel (4 KB)

    int t = threadIdx.x & 63;                                      // lane: pixels 2t, 2t+1
    int g = __builtin_amdgcn_readfirstlane((int)threadIdx.x >> 6); // group = wave id (uniform)

    // 2048 blocks = one (n,h) row each; bijective XCD-chunked swizzle so each
    // XCD walks 256 consecutive rows (2 images) -> vertical halo reuse in-L2.
    int bid = blockIdx.x;
    int row = (bid & 7) * (2048 / 8) + (bid >> 3);
    int n = row >> 7;
    int h = row & 127;

    // reflection-pad row indices (pad=1): -1 -> 1, 128 -> 126
    int ys[3];
    ys[0] = (h == 0)   ? 1   : h - 1;
    ys[1] = h;
    ys[2] = (h == 127) ? 126 : h + 1;

    // this wave's 32 input channels start at g*CPG
    const float* xg = x + ((size_t)n << 22) + ((size_t)(g * CPG) << 14);
    int w0 = t << 1;                  // first of this lane's two pixels

    float sig0[9], sig1[9];
#pragma unroll
    for (int o = 0; o < 9; o++) { sig0[o] = 0.f; sig1[o] = 0.f; }

    // ---- grouped conv (this wave's group): 1 f2 load + 2 shfl per (ci,ky) ----
    for (int ci = 0; ci < CPG; ci++) {
        const float* xc = xg + ((size_t)ci << 14);
        const float* wb = wf + (size_t)(g * 9) * (CPG * 9) + ci * 9;
#pragma unroll
        for (int ky = 0; ky < 3; ky++) {
            f2 ab = *reinterpret_cast<const f2*>(xc + (ys[ky] << 7) + w0);
            float a = ab.x, b = ab.y;
            float l = __shfl_up(b, 1);    // x[w0-1]; lane 0 self -> reflect
            float r = __shfl_down(a, 1);  // x[w0+2]; lane 63 self -> reflect
#pragma unroll
            for (int o = 0; o < 9; o++) {
                float wk0 = wb[o * (CPG * 9) + ky * 3 + 0];
                float wk1 = wb[o * (CPG * 9) + ky * 3 + 1];
                float wk2 = wb[o * (CPG * 9) + ky * 3 + 2];
                sig0[o] = fmaf(l, wk0, fmaf(a, wk1, fmaf(b, wk2, sig0[o])));
                sig1[o] = fmaf(a, wk0, fmaf(b, wk1, fmaf(r, wk2, sig1[o])));
            }
        }
    }

    // ---- BN + per-group (unnormalized) softmax ----
    float m0 = -3.0e38f, m1 = -3.0e38f;
#pragma unroll
    for (int o = 0; o < 9; o++) {
        float sc = scale[g * 9 + o], bi = bias[g * 9 + o];
        sig0[o] = fmaf(sig0[o], sc, bi);
        sig1[o] = fmaf(sig1[o], sc, bi);
        m0 = fmaxf(m0, sig0[o]);
        m1 = fmaxf(m1, sig1[o]);
    }
    float S0 = 0.f, S1 = 0.f;
#pragma unroll
    for (int o = 0; o < 9; o++) {
        sig0[o] = __expf(sig0[o] - m0);  // sig now holds E
        sig1[o] = __expf(sig1[o] - m1);
        S0 += sig0[o];
        S1 += sig1[o];
    }
    red_m[g][w0]     = m0;
    red_m[g][w0 + 1] = m1;
    red_s[g][w0]     = S0;
    red_s[g][w0 + 1] = S1;

    // ---- single barrier: combine the 8 groups' (m,S) into 1/denom ----
    __syncthreads();
    float d0 = 0.f, d1 = 0.f;
#pragma unroll
    for (int rg = 0; rg < NG; rg++) {
        d0 += red_s[rg][w0]     * __expf(red_m[rg][w0]     - m0);
        d1 += red_s[rg][w0 + 1] * __expf(red_m[rg][w0 + 1] - m1);
    }
    float inv0 = 1.f / d0, inv1 = 1.f / d1;
#pragma unroll
    for (int o = 0; o < 9; o++) { sig0[o] *= inv0; sig1[o] *= inv1; }

    // ---- weighted 9-tap sum for this wave's 32 channels ----
    size_t obase = ((size_t)n << 22) + ((size_t)(g * CPG) << 14)
                 + ((size_t)h << 7) + (size_t)w0;
    for (int ci = 0; ci < CPG; ci++) {
        const float* xc = xg + ((size_t)ci << 14);
        float o0 = 0.f, o1 = 0.f;
#pragma unroll
        for (int ky = 0; ky < 3; ky++) {
            f2 ab = *reinterpret_cast<const f2*>(xc + (ys[ky] << 7) + w0);
            float a = ab.x, b = ab.y;
            float l = __shfl_up(b, 1);
            float r = __shfl_down(a, 1);
            o0 = fmaf(l, sig0[ky * 3 + 0], fmaf(a, sig0[ky * 3 + 1], fmaf(b, sig0[ky * 3 + 2], o0)));
            o1 = fmaf(a, sig1[ky * 3 + 0], fmaf(b, sig1[ky * 3 + 1], fmaf(r, sig1[ky * 3 + 2], o1)));
        }
        f2 ov; ov.x = o0; ov.y = o1;
        __builtin_nontemporal_store(ov,
            reinterpret_cast<f2*>(out + obase + ((size_t)ci << 14)));
    }
}

extern "C" void kernel_launch(void* const* d_in, const int* in_sizes, int n_in,
                              void* d_out, int out_size, void* d_ws, size_t ws_size,
                              hipStream_t stream) {
    const float* x     = (const float*)d_in[0];
    const float* cw    = (const float*)d_in[1];
    const float* gamma = (const float*)d_in[2];
    const float* beta  = (const float*)d_in[3];
    const float* rmean = (const float*)d_in[4];
    const float* rvar  = (const float*)d_in[5];
    float* out = (float*)d_out;
    float* ws  = (float*)d_ws;   // needs 144*4 = 576 B

    hipLaunchKernelGGL(aaf_prep, dim3(1), dim3(128), 0, stream,
                       gamma, beta, rmean, rvar, ws);

    int blocks = NN * HH;               // 2048 blocks: one row x 8 groups each
    hipLaunchKernelGGL(aaf_main, dim3(blocks), dim3(512), 0, stream,
                       x, cw, ws, ws + NCH, out);
}

// Round 5
// 538.901 us; speedup vs baseline: 2.8711x; 1.0116x over previous
//
#include <hip/hip_runtime.h>

// Anti-alias filter: reflect-pad -> grouped conv (256->72, G=8, 3x3) -> BN ->
// softmax(72) -> per-pixel 9-tap weighted sum per channel.
// Shapes fixed: N=16, C=256, H=W=128, G=8, K=3, NCH=G*K*K=72, CPG=32.
//
// v5: 4 px/lane via float4 + 2 rows/wave.
// v4b was latency-bound (VALUBusy 47%, FETCH=input-once, VGPR only 32):
// per (ci,ky) one 8B load + 2 shfl fed just 54 FMAs. Now one 16B load +
// 2 shfl feeds 108 FMAs (4 independent pixel chains -> 4-way ILP), halving
// vmem+DS instructions per pixel. Wave = one group x 2 consecutive rows:
// lanes 0-31 = row A, lanes 32-63 = row B, 4 px per lane.
// Reflection padding stays in-register: at a row seam/edge the shfl result
// is replaced by the lane's own .y/.z component (reflect(x[-1])=x[1],
// reflect(x[128])=x[126]).
// Softmax: per-group (m,S), ONE barrier, f4 LDS exchange (ds_*_b128).

#define NN    16
#define CTOT  256
#define HH    128
#define WW    128
#define NG    8
#define CPG   32      // channels per group
#define NCH   72      // G*K*K conv output channels
#define BN_EPS 1e-5f

typedef float f2 __attribute__((ext_vector_type(2)));
typedef float f4 __attribute__((ext_vector_type(4)));

// ---- prep: BN scale/bias into ws ----
// ws layout (floats): [0,72) = scale, [72,144) = bias.
__global__ void aaf_prep(const float* __restrict__ gamma,
                         const float* __restrict__ beta,
                         const float* __restrict__ rmean,
                         const float* __restrict__ rvar,
                         float* __restrict__ ws) {
    int t = threadIdx.x;
    if (t < NCH) {
        float sc = gamma[t] * rsqrtf(rvar[t] + BN_EPS);
        ws[t]       = sc;
        ws[NCH + t] = beta[t] - rmean[t] * sc;
    }
}

// ---- main: block = 8 waves = 8 groups; wave = 2 rows x 128 px (4 px/lane) ----
__global__ __launch_bounds__(512, 4) void aaf_main(
    const float* __restrict__ x,
    const float* __restrict__ wf,     // fp32 conv weights OIHW flat (wave-uniform -> s_load)
    const float* __restrict__ scale,  // fp32 BN scale (72)
    const float* __restrict__ bias,   // fp32 BN bias  (72)
    float* __restrict__ out) {

    __shared__ f4 red_m[NG][64];      // per-group softmax max, 4 px per slot (4 KB)
    __shared__ f4 red_s[NG][64];      // per-group exp-sum (4 KB)

    int t  = threadIdx.x & 63;                                     // lane
    int g  = __builtin_amdgcn_readfirstlane((int)threadIdx.x >> 6);// group = wave id
    int half = t >> 5;                // 0: row A, 1: row B
    int tl   = t & 31;                // lane within row
    int w0   = tl << 2;               // first of this lane's 4 pixels

    // 1024 blocks = one row-pair each; bijective XCD-chunked swizzle: each XCD
    // walks 128 consecutive row-pairs (2 images) -> vertical halo reuse in-L2.
    int bid = blockIdx.x;
    int pr  = (bid & 7) * (1024 / 8) + (bid >> 3);
    int n   = pr >> 6;                // 64 row-pairs per image
    int h   = ((pr & 63) << 1) + half;

    // reflection-pad row indices (pad=1): -1 -> 1, 128 -> 126
    int ys[3];
    ys[0] = (h == 0)   ? 1   : h - 1;
    ys[1] = h;
    ys[2] = (h == 127) ? 126 : h + 1;

    // this wave's 32 input channels start at g*CPG
    const float* xg = x + ((size_t)n << 22) + ((size_t)(g * CPG) << 14);

    float s0[9], s1[9], s2[9], s3[9];
#pragma unroll
    for (int o = 0; o < 9; o++) { s0[o] = 0.f; s1[o] = 0.f; s2[o] = 0.f; s3[o] = 0.f; }

    // ---- grouped conv: 1 f4 load + 2 shfl feeds 108 FMA per (ci,ky) ----
    for (int ci = 0; ci < CPG; ci++) {
        const float* xc = xg + ((size_t)ci << 14);
        const float* wb = wf + (size_t)(g * 9) * (CPG * 9) + ci * 9;
#pragma unroll
        for (int ky = 0; ky < 3; ky++) {
            f4 v = *reinterpret_cast<const f4*>(xc + (ys[ky] << 7) + w0);
            float l = __shfl_up(v.w, 1);    // x[w0-1] from left lane
            l = (tl == 0) ? v.y : l;        // row left edge: reflect -> x[1]
            float r = __shfl_down(v.x, 1);  // x[w0+4] from right lane
            r = (tl == 31) ? v.z : r;       // row right edge: reflect -> x[126]
#pragma unroll
            for (int o = 0; o < 9; o++) {
                float wk0 = wb[o * (CPG * 9) + ky * 3 + 0];
                float wk1 = wb[o * (CPG * 9) + ky * 3 + 1];
                float wk2 = wb[o * (CPG * 9) + ky * 3 + 2];
                s0[o] = fmaf(l,   wk0, fmaf(v.x, wk1, fmaf(v.y, wk2, s0[o])));
                s1[o] = fmaf(v.x, wk0, fmaf(v.y, wk1, fmaf(v.z, wk2, s1[o])));
                s2[o] = fmaf(v.y, wk0, fmaf(v.z, wk1, fmaf(v.w, wk2, s2[o])));
                s3[o] = fmaf(v.z, wk0, fmaf(v.w, wk1, fmaf(r,   wk2, s3[o])));
            }
        }
    }

    // ---- BN + per-group (unnormalized) softmax over this group's 9 ----
    float m0 = -3.0e38f, m1 = -3.0e38f, m2 = -3.0e38f, m3 = -3.0e38f;
#pragma unroll
    for (int o = 0; o < 9; o++) {
        float sc = scale[g * 9 + o], bi = bias[g * 9 + o];
        s0[o] = fmaf(s0[o], sc, bi);  m0 = fmaxf(m0, s0[o]);
        s1[o] = fmaf(s1[o], sc, bi);  m1 = fmaxf(m1, s1[o]);
        s2[o] = fmaf(s2[o], sc, bi);  m2 = fmaxf(m2, s2[o]);
        s3[o] = fmaf(s3[o], sc, bi);  m3 = fmaxf(m3, s3[o]);
    }
    float S0 = 0.f, S1 = 0.f, S2 = 0.f, S3 = 0.f;
#pragma unroll
    for (int o = 0; o < 9; o++) {
        s0[o] = __expf(s0[o] - m0);  S0 += s0[o];   // s* now holds E
        s1[o] = __expf(s1[o] - m1);  S1 += s1[o];
        s2[o] = __expf(s2[o] - m2);  S2 += s2[o];
        s3[o] = __expf(s3[o] - m3);  S3 += s3[o];
    }
    {
        f4 mm; mm.x = m0; mm.y = m1; mm.z = m2; mm.w = m3;
        f4 ss; ss.x = S0; ss.y = S1; ss.z = S2; ss.w = S3;
        red_m[g][t] = mm;             // slot t = pixels [half*128 + w0 .. +3]
        red_s[g][t] = ss;
    }

    // ---- single barrier: combine the 8 groups' (m,S) into 1/denom ----
    __syncthreads();
    float d0 = 0.f, d1 = 0.f, d2 = 0.f, d3 = 0.f;
#pragma unroll
    for (int rg = 0; rg < NG; rg++) {
        f4 mm = red_m[rg][t];
        f4 ss = red_s[rg][t];
        d0 += ss.x * __expf(mm.x - m0);
        d1 += ss.y * __expf(mm.y - m1);
        d2 += ss.z * __expf(mm.z - m2);
        d3 += ss.w * __expf(mm.w - m3);
    }
    float i0 = 1.f / d0, i1 = 1.f / d1, i2 = 1.f / d2, i3 = 1.f / d3;
#pragma unroll
    for (int o = 0; o < 9; o++) { s0[o] *= i0; s1[o] *= i1; s2[o] *= i2; s3[o] *= i3; }

    // ---- weighted 9-tap sum for this wave's 32 channels ----
    size_t obase = ((size_t)n << 22) + ((size_t)(g * CPG) << 14)
                 + ((size_t)h << 7) + (size_t)w0;
    for (int ci = 0; ci < CPG; ci++) {
        const float* xc = xg + ((size_t)ci << 14);
        float o0 = 0.f, o1 = 0.f, o2 = 0.f, o3 = 0.f;
#pragma unroll
        for (int ky = 0; ky < 3; ky++) {
            f4 v = *reinterpret_cast<const f4*>(xc + (ys[ky] << 7) + w0);
            float l = __shfl_up(v.w, 1);
            l = (tl == 0) ? v.y : l;
            float r = __shfl_down(v.x, 1);
            r = (tl == 31) ? v.z : r;
            float e0 = s0[ky * 3 + 0], e1 = s0[ky * 3 + 1], e2 = s0[ky * 3 + 2];
            o0 = fmaf(l,   e0, fmaf(v.x, e1, fmaf(v.y, e2, o0)));
            e0 = s1[ky * 3 + 0]; e1 = s1[ky * 3 + 1]; e2 = s1[ky * 3 + 2];
            o1 = fmaf(v.x, e0, fmaf(v.y, e1, fmaf(v.z, e2, o1)));
            e0 = s2[ky * 3 + 0]; e1 = s2[ky * 3 + 1]; e2 = s2[ky * 3 + 2];
            o2 = fmaf(v.y, e0, fmaf(v.z, e1, fmaf(v.w, e2, o2)));
            e0 = s3[ky * 3 + 0]; e1 = s3[ky * 3 + 1]; e2 = s3[ky * 3 + 2];
            o3 = fmaf(v.z, e0, fmaf(v.w, e1, fmaf(r,   e2, o3)));
        }
        f4 ov; ov.x = o0; ov.y = o1; ov.z = o2; ov.w = o3;
        __builtin_nontemporal_store(ov,
            reinterpret_cast<f4*>(out + obase + ((size_t)ci << 14)));
    }
}

extern "C" void kernel_launch(void* const* d_in, const int* in_sizes, int n_in,
                              void* d_out, int out_size, void* d_ws, size_t ws_size,
                              hipStream_t stream) {
    const float* x     = (const float*)d_in[0];
    const float* cw    = (const float*)d_in[1];
    const float* gamma = (const float*)d_in[2];
    const float* beta  = (const float*)d_in[3];
    const float* rmean = (const float*)d_in[4];
    const float* rvar  = (const float*)d_in[5];
    float* out = (float*)d_out;
    float* ws  = (float*)d_ws;   // needs 144*4 = 576 B

    hipLaunchKernelGGL(aaf_prep, dim3(1), dim3(128), 0, stream,
                       gamma, beta, rmean, rvar, ws);

    int blocks = NN * HH / 2;           // 1024 blocks: one row-pair x 8 groups
    hipLaunchKernelGGL(aaf_main, dim3(blocks), dim3(512), 0, stream,
                       x, cw, ws, ws + NCH, out);
}